// Round 14
// baseline (2819.671 us; speedup 1.0000x reference)
//
#include <hip/hip_runtime.h>
#include <stdint.h>

#define B_ 64
#define T_ 4096
#define C_ 32

typedef unsigned int uint32;
typedef unsigned short ushort16;
typedef unsigned int uint32x2 __attribute__((ext_vector_type(2)));
typedef _Float16 half2v __attribute__((ext_vector_type(2)));

__device__ __forceinline__ float bf2f(ushort16 u) {
    return __uint_as_float(((uint32)u) << 16);
}
__device__ __forceinline__ uint32 f2bf_bits(float f) {  // round-to-nearest-even bf16
    uint32 u = __float_as_uint(f);
    uint32 r = u + 0x7fffu + ((u >> 16) & 1u);
    return r >> 16;
}
__device__ __forceinline__ void unpack2(uint32 u, float& f0, float& f1) {
    f0 = __uint_as_float(u << 16);
    f1 = __uint_as_float(u & 0xffff0000u);
}
__device__ __forceinline__ float fast_sigmoid(float x) {
    float e = __builtin_amdgcn_exp2f(x * -1.442695040889f);
    return __builtin_amdgcn_rcpf(1.0f + e);
}
// cvt_pkrtz returns __fp16x2; bit-cast to _Float16x2 for fdot2
__device__ __forceinline__ half2v pkrtz(float a, float b) {
    return __builtin_bit_cast(half2v, __builtin_amdgcn_cvt_pkrtz(a, b));
}

// half-swap across the two 32-lane halves (verified rounds 7/8/11, absmax 0).
__device__ __forceinline__ void half_swap(uint32 vb, uint32& zb, uint32& nb) {
#if __has_builtin(__builtin_amdgcn_permlane32_swap)
    uint32x2 sw = __builtin_amdgcn_permlane32_swap(vb, vb, false, false);
    zb = sw.x; nb = sw.y;
#else
    uint32 a = vb, b = vb;
    asm("v_permlane32_swap_b32 %0, %1" : "+v"(a), "+v"(b));
    zb = a; nb = b;
#endif
}

// ---------------------------------------------------------------------------
// Kernel A: conv_in + down1-5 + feat1-5 + gi1 (input gates for gru1, bf16)
// ---------------------------------------------------------------------------
__global__ __launch_bounds__(256) void kA(
    const float* __restrict__ x, const float* __restrict__ w_in, const float* __restrict__ b_in,
    const float* __restrict__ W32, const float* __restrict__ B32,
    const float* __restrict__ wih1, const float* __restrict__ bih1, const float* __restrict__ bhh1,
    ushort16* __restrict__ gi1)
{
    const int row = blockIdx.x * 256 + threadIdx.x;  // 0 .. B*T-1
    const float4* xr = (const float4*)(x + (size_t)row * 8);
    float4 x0 = xr[0], x1 = xr[1];
    float xv[8] = {x0.x, x0.y, x0.z, x0.w, x1.x, x1.y, x1.z, x1.w};

    float h[C_], hn[C_];
#pragma unroll
    for (int o = 0; o < C_; o++) {
        float a = b_in[o];
#pragma unroll
        for (int j = 0; j < 8; j++) a = fmaf(xv[j], w_in[o * 8 + j], a);
        h[o] = fmaxf(a, 0.0f);
    }
#pragma unroll 1
    for (int L = 0; L < 10; L++) {
        const float* W = W32 + L * C_ * C_;
        const float* bb = B32 + L * C_;
#pragma unroll
        for (int o = 0; o < C_; o++) {
            float a = bb[o];
#pragma unroll
            for (int j = 0; j < C_; j++) a = fmaf(h[j], W[o * C_ + j], a);
            hn[o] = fmaxf(a, 0.0f);
        }
#pragma unroll
        for (int o = 0; o < C_; o++) h[o] = hn[o];
    }
    // gi1: gates 32..95 only (r-gate is dead). Fold bih+bhh.
    uint4* dst = (uint4*)(gi1 + (size_t)row * 64);
#pragma unroll
    for (int k = 0; k < 8; k++) {
        uint32 wbuf[4];
#pragma unroll
        for (int p = 0; p < 4; p++) {
            int o0 = k * 8 + p * 2;
            float a0 = bih1[32 + o0] + bhh1[32 + o0];
            float a1 = bih1[33 + o0] + bhh1[33 + o0];
#pragma unroll
            for (int j = 0; j < C_; j++) {
                a0 = fmaf(h[j], wih1[(32 + o0) * C_ + j], a0);
                a1 = fmaf(h[j], wih1[(33 + o0) * C_ + j], a1);
            }
            wbuf[p] = f2bf_bits(a0) | (f2bf_bits(a1) << 16);
        }
        dst[k] = make_uint4(wbuf[0], wbuf[1], wbuf[2], wbuf[3]);
    }
}

// ---------------------------------------------------------------------------
// GRU scan, TWO independent sequences per wave (A and B), steps interleaved
// so each chain's latency hides under the other's issue.
// Chain A is always forward (batch blockIdx.x, gate columns colA).
// Chain B: batch blockIdx.x + bOffB, reversed iff revB, gate columns colB.
// Per-chain structure is round-11's verified kernel: raw gbuf prefetch,
// 16x v_dot2_f32_f16 in 4 chains, permlane32_swap, DPP+pkrtz+16 readlane.
// ---------------------------------------------------------------------------
__global__ __launch_bounds__(64, 1) void kGru2(
    const ushort16* __restrict__ giA, const ushort16* __restrict__ giB,
    const float* __restrict__ whhA, const float* __restrict__ whhB,
    ushort16* __restrict__ out, int outStride, int colA, int colB,
    int bOffB, int revB)
{
    const int lane = threadIdx.x;
    const bool isZ = lane < 32;
    const int bA = blockIdx.x;
    const int bB = blockIdx.x + bOffB;

    // z: sigmoid(x) = rcp(1+2^(-x*log2e));  n: tanh(x) = 2*rcp(1+2^(-2x*log2e))-1
    const float cs = isZ ? -1.442695040889f : -2.885390081777f;
    const float cm = isZ ? 1.0f : 2.0f;
    const float ca = isZ ? 0.0f : -1.0f;

    // recurrent weights (f16-packed) for both chains
    half2v wpkA[16], wpkB[16];
    {
        const float4* wrA = (const float4*)(whhA + (32 + lane) * 32);
        const float4* wrB = (const float4*)(whhB + (32 + lane) * 32);
#pragma unroll
        for (int k = 0; k < 8; k++) {
            float4 qa = wrA[k], qb = wrB[k];
            wpkA[2 * k]     = pkrtz(qa.x, qa.y);
            wpkA[2 * k + 1] = pkrtz(qa.z, qa.w);
            wpkB[2 * k]     = pkrtz(qb.x, qb.y);
            wpkB[2 * k + 1] = pkrtz(qb.z, qb.w);
        }
    }

    uint32 hpA[16], hpB[16];  // packed f16 h pairs, wave-uniform (SGPRs)
#pragma unroll
    for (int j = 0; j < 16; j++) { hpA[j] = 0; hpB[j] = 0; }
    float h_mineA = 0.0f, h_mineB = 0.0f;

    const ushort16* gpA = giA + (size_t)bA * T_ * 64 + lane;
    const ushort16* gpB = giB + (size_t)bB * T_ * 64 + lane;

    ushort16 gbufA[8], gbufB[8];  // raw 8-deep prefetch
#pragma unroll
    for (int u = 0; u < 8; u++) {
        gbufA[u] = gpA[(size_t)u * 64];
        int tB = revB ? (T_ - 1 - u) : u;
        gbufB[u] = gpB[(size_t)tB * 64];
    }

    for (int s0 = 0; s0 < T_; s0 += 8) {
#pragma unroll
        for (int u = 0; u < 8; u++) {
            const int s = s0 + u;
            int sp = s + 8; if (sp > T_ - 1) sp = T_ - 1;

            // ---- issue both dots first (independent chains) ----
            float gA = bf2f(gbufA[u]);
            gbufA[u] = gpA[(size_t)sp * 64];
            float a0 = gA, a1 = 0.f, a2 = 0.f, a3 = 0.f;
#pragma unroll
            for (int j = 0; j < 4; j++) {
                a0 = __builtin_amdgcn_fdot2(wpkA[j],      __builtin_bit_cast(half2v, hpA[j]),      a0, false);
                a1 = __builtin_amdgcn_fdot2(wpkA[j + 4],  __builtin_bit_cast(half2v, hpA[j + 4]),  a1, false);
                a2 = __builtin_amdgcn_fdot2(wpkA[j + 8],  __builtin_bit_cast(half2v, hpA[j + 8]),  a2, false);
                a3 = __builtin_amdgcn_fdot2(wpkA[j + 12], __builtin_bit_cast(half2v, hpA[j + 12]), a3, false);
            }

            float gB = bf2f(gbufB[u]);
            int tpB = revB ? (T_ - 1 - sp) : sp;
            gbufB[u] = gpB[(size_t)tpB * 64];
            float c0 = gB, c1 = 0.f, c2 = 0.f, c3 = 0.f;
#pragma unroll
            for (int j = 0; j < 4; j++) {
                c0 = __builtin_amdgcn_fdot2(wpkB[j],      __builtin_bit_cast(half2v, hpB[j]),      c0, false);
                c1 = __builtin_amdgcn_fdot2(wpkB[j + 4],  __builtin_bit_cast(half2v, hpB[j + 4]),  c1, false);
                c2 = __builtin_amdgcn_fdot2(wpkB[j + 8],  __builtin_bit_cast(half2v, hpB[j + 8]),  c2, false);
                c3 = __builtin_amdgcn_fdot2(wpkB[j + 12], __builtin_bit_cast(half2v, hpB[j + 12]), c3, false);
            }

            // ---- finish chain A ----
            float gsA = (a0 + a1) + (a2 + a3);
            float eA = __builtin_amdgcn_exp2f(gsA * cs);
            float rA = __builtin_amdgcn_rcpf(1.0f + eA);
            float vA = fmaf(cm, rA, ca);
            uint32 zA, nA;
            half_swap(__float_as_uint(vA), zA, nA);
            float hnvA = fmaf(__uint_as_float(zA), h_mineA - __uint_as_float(nA), __uint_as_float(nA));
            h_mineA = hnvA;
            if (lane < 32)
                out[((size_t)bA * T_ + s) * outStride + colA + lane] = (ushort16)f2bf_bits(hnvA);
            uint32 hbA = __float_as_uint(hnvA);
            uint32 nbA = (uint32)__builtin_amdgcn_mov_dpp((int)hbA, 0xB1, 0xF, 0xF, true);
            uint32 pkA = __builtin_bit_cast(uint32, pkrtz(hnvA, __uint_as_float(nbA)));
#pragma unroll
            for (int j = 0; j < 16; j++)
                hpA[j] = (uint32)__builtin_amdgcn_readlane(pkA, 2 * j);

            // ---- finish chain B ----
            float gsB = (c0 + c1) + (c2 + c3);
            float eB = __builtin_amdgcn_exp2f(gsB * cs);
            float rB = __builtin_amdgcn_rcpf(1.0f + eB);
            float vB = fmaf(cm, rB, ca);
            uint32 zB, nB;
            half_swap(__float_as_uint(vB), zB, nB);
            float hnvB = fmaf(__uint_as_float(zB), h_mineB - __uint_as_float(nB), __uint_as_float(nB));
            h_mineB = hnvB;
            int tB = revB ? (T_ - 1 - s) : s;
            if (lane < 32)
                out[((size_t)bB * T_ + tB) * outStride + colB + lane] = (ushort16)f2bf_bits(hnvB);
            uint32 hbB = __float_as_uint(hnvB);
            uint32 nbB = (uint32)__builtin_amdgcn_mov_dpp((int)hbB, 0xB1, 0xF, 0xF, true);
            uint32 pkB = __builtin_bit_cast(uint32, pkrtz(hnvB, __uint_as_float(nbB)));
#pragma unroll
            for (int j = 0; j < 16; j++)
                hpB[j] = (uint32)__builtin_amdgcn_readlane(pkB, 2 * j);
        }
    }
}

// ---------------------------------------------------------------------------
// Kernel C: dec1-3 + gi2 forward + gi2 reverse
// ---------------------------------------------------------------------------
__global__ __launch_bounds__(256) void kC(
    const ushort16* __restrict__ ys1,
    const float* __restrict__ W32, const float* __restrict__ B32,
    const float* __restrict__ wih2, const float* __restrict__ bih2, const float* __restrict__ bhh2,
    const float* __restrict__ wih2r, const float* __restrict__ bih2r, const float* __restrict__ bhh2r,
    ushort16* __restrict__ gi2f, ushort16* __restrict__ gi2r)
{
    const int row = blockIdx.x * 256 + threadIdx.x;
    float h[C_], hn[C_];
    const uint4* src = (const uint4*)(ys1 + (size_t)row * 32);
#pragma unroll
    for (int k = 0; k < 4; k++) {
        uint4 v = src[k];
        unpack2(v.x, h[8 * k + 0], h[8 * k + 1]);
        unpack2(v.y, h[8 * k + 2], h[8 * k + 3]);
        unpack2(v.z, h[8 * k + 4], h[8 * k + 5]);
        unpack2(v.w, h[8 * k + 6], h[8 * k + 7]);
    }
#pragma unroll 1
    for (int L = 10; L < 13; L++) {
        const float* W = W32 + L * C_ * C_;
        const float* bb = B32 + L * C_;
#pragma unroll
        for (int o = 0; o < C_; o++) {
            float a = bb[o];
#pragma unroll
            for (int j = 0; j < C_; j++) a = fmaf(h[j], W[o * C_ + j], a);
            hn[o] = fmaxf(a, 0.0f);
        }
#pragma unroll
        for (int o = 0; o < C_; o++) h[o] = hn[o];
    }
#pragma unroll 1
    for (int d = 0; d < 2; d++) {
        const float* wih = d ? wih2r : wih2;
        const float* bi = d ? bih2r : bih2;
        const float* bh = d ? bhh2r : bhh2;
        uint4* dst = (uint4*)((d ? gi2r : gi2f) + (size_t)row * 64);
#pragma unroll
        for (int k = 0; k < 8; k++) {
            uint32 wbuf[4];
#pragma unroll
            for (int p = 0; p < 4; p++) {
                int o0 = k * 8 + p * 2;
                float a0 = bi[32 + o0] + bh[32 + o0];
                float a1 = bi[33 + o0] + bh[33 + o0];
#pragma unroll
                for (int j = 0; j < C_; j++) {
                    a0 = fmaf(h[j], wih[(32 + o0) * C_ + j], a0);
                    a1 = fmaf(h[j], wih[(33 + o0) * C_ + j], a1);
                }
                wbuf[p] = f2bf_bits(a0) | (f2bf_bits(a1) << 16);
            }
            dst[k] = make_uint4(wbuf[0], wbuf[1], wbuf[2], wbuf[3]);
        }
    }
}

// ---------------------------------------------------------------------------
// Kernel E: up1 (64->32) + up2-5 + out head + sigmoid
// ---------------------------------------------------------------------------
__global__ __launch_bounds__(256) void kE(
    const ushort16* __restrict__ hcat,
    const float* __restrict__ w_up1, const float* __restrict__ b_up1,
    const float* __restrict__ W32, const float* __restrict__ B32,
    const float* __restrict__ w_out, const float* __restrict__ b_out,
    float* __restrict__ outp)
{
    const int row = blockIdx.x * 256 + threadIdx.x;
    float h64[64];
    const uint4* src = (const uint4*)(hcat + (size_t)row * 64);
#pragma unroll
    for (int k = 0; k < 8; k++) {
        uint4 v = src[k];
        unpack2(v.x, h64[8 * k + 0], h64[8 * k + 1]);
        unpack2(v.y, h64[8 * k + 2], h64[8 * k + 3]);
        unpack2(v.z, h64[8 * k + 4], h64[8 * k + 5]);
        unpack2(v.w, h64[8 * k + 6], h64[8 * k + 7]);
    }
    float h[C_], hn[C_];
#pragma unroll
    for (int o = 0; o < C_; o++) {
        float a = b_up1[o];
#pragma unroll
        for (int j = 0; j < 64; j++) a = fmaf(h64[j], w_up1[o * 64 + j], a);
        h[o] = fmaxf(a, 0.0f);
    }
#pragma unroll 1
    for (int L = 13; L < 17; L++) {
        const float* W = W32 + L * C_ * C_;
        const float* bb = B32 + L * C_;
#pragma unroll
        for (int o = 0; o < C_; o++) {
            float a = bb[o];
#pragma unroll
            for (int j = 0; j < C_; j++) a = fmaf(h[j], W[o * C_ + j], a);
            hn[o] = fmaxf(a, 0.0f);
        }
#pragma unroll
        for (int o = 0; o < C_; o++) h[o] = hn[o];
    }
    float r0 = b_out[0], r1 = b_out[1];
#pragma unroll
    for (int j = 0; j < C_; j++) {
        r0 = fmaf(h[j], w_out[j], r0);
        r1 = fmaf(h[j], w_out[32 + j], r1);
    }
    float2 res = make_float2(fast_sigmoid(r0), fast_sigmoid(r1));
    ((float2*)outp)[row] = res;
}

// ---------------------------------------------------------------------------
extern "C" void kernel_launch(void* const* d_in, const int* in_sizes, int n_in,
                              void* d_out, int out_size, void* d_ws, size_t ws_size,
                              hipStream_t stream) {
    const float* x     = (const float*)d_in[0];
    const float* w_in  = (const float*)d_in[1];
    const float* b_in  = (const float*)d_in[2];
    const float* W32   = (const float*)d_in[3];
    const float* B32   = (const float*)d_in[4];
    const float* w_up1 = (const float*)d_in[5];
    const float* b_up1 = (const float*)d_in[6];
    const float* w_out = (const float*)d_in[7];
    const float* b_out = (const float*)d_in[8];
    const float* wih1  = (const float*)d_in[9];
    const float* whh1  = (const float*)d_in[10];
    const float* bih1  = (const float*)d_in[11];
    const float* bhh1  = (const float*)d_in[12];
    const float* wih2  = (const float*)d_in[13];
    const float* whh2  = (const float*)d_in[14];
    const float* bih2  = (const float*)d_in[15];
    const float* bhh2  = (const float*)d_in[16];
    const float* wih2r = (const float*)d_in[17];
    const float* whh2r = (const float*)d_in[18];
    const float* bih2r = (const float*)d_in[19];
    const float* bhh2r = (const float*)d_in[20];

    const size_t NB = (size_t)B_ * T_;  // 262144 rows
    // Workspace layout (112 MB): gi2f aliases gi1 (dead after gru1).
    ushort16* gi1  = (ushort16*)d_ws;        // [NB][64] bf16 : 32 MB
    ushort16* gi2f = gi1;                    // aliases gi1
    ushort16* gi2r = gi1  + NB * 64;         // 32 MB
    ushort16* ys1  = gi2r + NB * 64;         // [NB][32] bf16 : 16 MB
    ushort16* hcat = ys1  + NB * 32;         // [NB][64] bf16 : 32 MB

    const int rowBlocks = (int)(NB / 256);   // 1024

    kA<<<rowBlocks, 256, 0, stream>>>(x, w_in, b_in, W32, B32, wih1, bih1, bhh1, gi1);
    // gru1: 32 waves, each runs batches b and b+32 (both forward, same weights)
    kGru2<<<32, 64, 0, stream>>>(gi1, gi1, whh1, whh1, ys1, 32, 0, 0, 32, 0);
    kC<<<rowBlocks, 256, 0, stream>>>(ys1, W32, B32, wih2, bih2, bhh2,
                                      wih2r, bih2r, bhh2r, gi2f, gi2r);
    // gru2: 64 waves, each runs fwd chain (A) and rev chain (B) of batch b
    kGru2<<<64, 64, 0, stream>>>(gi2f, gi2r, whh2, whh2r, hcat, 64, 0, 32, 0, 1);
    kE<<<rowBlocks, 256, 0, stream>>>(hcat, w_up1, b_up1, W32, B32, w_out, b_out,
                                      (float*)d_out);
}

// Round 16
// 1646.233 us; speedup vs baseline: 1.7128x; 1.7128x over previous
//
#include <hip/hip_runtime.h>
#include <stdint.h>

#define B_ 64
#define T_ 4096
#define C_ 32

typedef unsigned int uint32;
typedef unsigned short ushort16;
typedef unsigned int uint32x2 __attribute__((ext_vector_type(2)));
typedef _Float16 half2v __attribute__((ext_vector_type(2)));

__device__ __forceinline__ float bf2f(ushort16 u) {
    return __uint_as_float(((uint32)u) << 16);
}
__device__ __forceinline__ uint32 f2bf_bits(float f) {  // round-to-nearest-even bf16
    uint32 u = __float_as_uint(f);
    uint32 r = u + 0x7fffu + ((u >> 16) & 1u);
    return r >> 16;
}
__device__ __forceinline__ void unpack2(uint32 u, float& f0, float& f1) {
    f0 = __uint_as_float(u << 16);
    f1 = __uint_as_float(u & 0xffff0000u);
}
__device__ __forceinline__ float fast_sigmoid(float x) {
    float e = __builtin_amdgcn_exp2f(x * -1.442695040889f);
    return __builtin_amdgcn_rcpf(1.0f + e);
}
// cvt_pkrtz returns __fp16x2; bit-cast to _Float16x2
__device__ __forceinline__ half2v pkrtz(float a, float b) {
    return __builtin_bit_cast(half2v, __builtin_amdgcn_cvt_pkrtz(a, b));
}
__device__ __forceinline__ uint32 packpair(float a, float b) {
    return __builtin_bit_cast(uint32, pkrtz(a, b));
}
// packed-f16 dot2 accumulate
__device__ __forceinline__ float fd2(uint32 wu, uint32 hu, float acc) {
    return __builtin_amdgcn_fdot2(__builtin_bit_cast(half2v, wu),
                                  __builtin_bit_cast(half2v, hu), acc, false);
}

// half-swap across the two 32-lane halves (verified rounds 7/8/11, absmax 0).
__device__ __forceinline__ void half_swap(uint32 vb, uint32& zb, uint32& nb) {
#if __has_builtin(__builtin_amdgcn_permlane32_swap)
    uint32x2 sw = __builtin_amdgcn_permlane32_swap(vb, vb, false, false);
    zb = sw.x; nb = sw.y;
#else
    uint32 a = vb, b = vb;
    asm("v_permlane32_swap_b32 %0, %1" : "+v"(a), "+v"(b));
    zb = a; nb = b;
#endif
}

#define CSZ (-1.442695040889f)
#define CSN (-2.885390081777f)

// packed-weight region offsets (u32 words), placed after hcat in d_ws
#define OFF_W32P   0        // [17][32][16]  = 8704
#define OFF_WINP   8704     // [32][4]       = 128
#define OFF_WUP1P  8832     // [32][32]      = 1024
#define OFF_WIH1P  9856     // [64][16]      = 1024
#define OFF_WIH2P  10880    // [64][16]      = 1024
#define OFF_WIH2RP 11904    // [64][16]      = 1024
#define NPACK      12928

// ---------------------------------------------------------------------------
// kPack: one-time f32 -> packed f16-pair conversion of all conv/gi weights.
// ---------------------------------------------------------------------------
__global__ __launch_bounds__(256) void kPack(
    const float* __restrict__ w_in, const float* __restrict__ W32,
    const float* __restrict__ w_up1,
    const float* __restrict__ wih1, const float* __restrict__ wih2,
    const float* __restrict__ wih2r, uint32* __restrict__ dst)
{
    const int t = threadIdx.x;
#pragma unroll 1
    for (int i = t; i < 8704; i += 256) dst[OFF_W32P + i]  = packpair(W32[2*i],  W32[2*i+1]);
#pragma unroll 1
    for (int i = t; i < 128; i += 256)  dst[OFF_WINP + i]  = packpair(w_in[2*i], w_in[2*i+1]);
#pragma unroll 1
    for (int i = t; i < 1024; i += 256) dst[OFF_WUP1P + i] = packpair(w_up1[2*i], w_up1[2*i+1]);
    // gi weights: rows 32..95 of wih (r-gate dead) = contiguous from offset 1024
#pragma unroll 1
    for (int i = t; i < 1024; i += 256) dst[OFF_WIH1P + i]  = packpair(wih1[1024+2*i],  wih1[1024+2*i+1]);
#pragma unroll 1
    for (int i = t; i < 1024; i += 256) dst[OFF_WIH2P + i]  = packpair(wih2[1024+2*i],  wih2[1024+2*i+1]);
#pragma unroll 1
    for (int i = t; i < 1024; i += 256) dst[OFF_WIH2RP + i] = packpair(wih2r[1024+2*i], wih2r[1024+2*i+1]);
}

// ---------------------------------------------------------------------------
// Kernel A: conv_in + down1-5 + feat1-5 + gi1 (cs-prescaled, bf16)
// Conv inner loops use v_dot2_f32_f16 with packed uniform weights (SGPR).
// ---------------------------------------------------------------------------
__global__ __launch_bounds__(256) void kA(
    const float* __restrict__ x, const float* __restrict__ b_in,
    const uint32* __restrict__ wp, const float* __restrict__ B32,
    const float* __restrict__ bih1, const float* __restrict__ bhh1,
    ushort16* __restrict__ gi1)
{
    const int row = blockIdx.x * 256 + threadIdx.x;  // 0 .. B*T-1
    const float4* xr = (const float4*)(x + (size_t)row * 8);
    float4 x0 = xr[0], x1 = xr[1];
    uint32 xpk[4] = {packpair(x0.x, x0.y), packpair(x0.z, x0.w),
                     packpair(x1.x, x1.y), packpair(x1.z, x1.w)};

    float h[C_], hn[C_];
    const uint32* winp = wp + OFF_WINP;
#pragma unroll
    for (int o = 0; o < C_; o++) {
        float a = b_in[o];
#pragma unroll
        for (int j = 0; j < 4; j++) a = fd2(winp[o * 4 + j], xpk[j], a);
        h[o] = fmaxf(a, 0.0f);
    }
    uint32 hpk[16];
#pragma unroll 1
    for (int L = 0; L < 10; L++) {
        const uint32* Wp = wp + OFF_W32P + L * 512;
        const float* bb = B32 + L * C_;
#pragma unroll
        for (int k = 0; k < 16; k++) hpk[k] = packpair(h[2*k], h[2*k+1]);
#pragma unroll
        for (int o = 0; o < C_; o++) {
            float a = bb[o];
#pragma unroll
            for (int j = 0; j < 16; j++) a = fd2(Wp[o * 16 + j], hpk[j], a);
            hn[o] = fmaxf(a, 0.0f);
        }
#pragma unroll
        for (int o = 0; o < C_; o++) h[o] = hn[o];
    }
    // gi1: gates 32..95, fold bih+bhh, PRE-SCALED by cs (z: CSZ, n: CSN)
#pragma unroll
    for (int k = 0; k < 16; k++) hpk[k] = packpair(h[2*k], h[2*k+1]);
    const uint32* wihp = wp + OFF_WIH1P;
    uint4* dst = (uint4*)(gi1 + (size_t)row * 64);
#pragma unroll
    for (int k = 0; k < 8; k++) {
        uint32 wbuf[4];
#pragma unroll
        for (int p = 0; p < 4; p++) {
            int o0 = k * 8 + p * 2;
            float cs0 = (o0 < 32) ? CSZ : CSN;
            float a0 = bih1[32 + o0] + bhh1[32 + o0];
            float a1 = bih1[33 + o0] + bhh1[33 + o0];
#pragma unroll
            for (int j = 0; j < 16; j++) {
                a0 = fd2(wihp[o0 * 16 + j],       hpk[j], a0);
                a1 = fd2(wihp[(o0 + 1) * 16 + j], hpk[j], a1);
            }
            wbuf[p] = f2bf_bits(a0 * cs0) | (f2bf_bits(a1 * cs0) << 16);
        }
        dst[k] = make_uint4(wbuf[0], wbuf[1], wbuf[2], wbuf[3]);
    }
}

// ---------------------------------------------------------------------------
// GRU scan (round-11 verified structure; 403 cyc/step measured).
// Changes vs r11: cs folded into wpk at init and into gi at producer ->
// no per-step gs*cs mul on the dependent chain. Everything else identical.
// ---------------------------------------------------------------------------
__global__ __launch_bounds__(64, 1) void kGru(
    const ushort16* __restrict__ gi_f, const ushort16* __restrict__ gi_r,
    const float* __restrict__ whh_f, const float* __restrict__ whh_r,
    ushort16* __restrict__ out, int outStride, int col_f, int col_r)
{
    const int blk = blockIdx.x;
    const bool rev = blk >= 64;
    const int b = blk & 63;
    const int lane = threadIdx.x;
    const bool isZ = lane < 32;

    const ushort16* gi = rev ? gi_r : gi_f;
    const float* whh = rev ? whh_r : whh_f;
    const int colbase = rev ? col_r : col_f;

    const float cs = isZ ? CSZ : CSN;
    const float cm = isZ ? 1.0f : 2.0f;
    const float ca = isZ ? 0.0f : -1.0f;

    const float4* wr = (const float4*)(whh + (32 + lane) * 32);
    // recurrent weights packed as f16 pairs, PRE-SCALED by cs
    half2v wpk[16];
#pragma unroll
    for (int k = 0; k < 8; k++) {
        float4 q = wr[k];
        wpk[2 * k]     = pkrtz(q.x * cs, q.y * cs);
        wpk[2 * k + 1] = pkrtz(q.z * cs, q.w * cs);
    }
    uint32 hp[16];  // packed f16 pairs of h, wave-uniform (SGPRs)
#pragma unroll
    for (int j = 0; j < 16; j++) hp[j] = 0;

    float h_mine = 0.0f;  // h[lane&31], maintained in all lanes

    const ushort16* gp = gi + (size_t)b * T_ * 64 + lane;

    ushort16 gbuf[8];  // 8-deep RAW prefetch of gi (convert at use, 8 steps later)
#pragma unroll
    for (int u = 0; u < 8; u++) {
        int t = rev ? (T_ - 1 - u) : u;
        gbuf[u] = gp[(size_t)t * 64];
    }

    for (int s0 = 0; s0 < T_; s0 += 8) {
#pragma unroll
        for (int u = 0; u < 8; u++) {
            const int s = s0 + u;
            float g = bf2f(gbuf[u]);   // loaded 8 steps ago: no wait (already cs-scaled)
            int sp = s + 8; if (sp > T_ - 1) sp = T_ - 1;
            int tp = rev ? (T_ - 1 - sp) : sp;
            gbuf[u] = gp[(size_t)tp * 64];

            // dot(whh_row*cs, h): 16 dot2 in 4 chains
            float a0 = g, a1 = 0.f, a2 = 0.f, a3 = 0.f;
#pragma unroll
            for (int j = 0; j < 4; j++) {
                a0 = __builtin_amdgcn_fdot2(wpk[j],      __builtin_bit_cast(half2v, hp[j]),      a0, false);
                a1 = __builtin_amdgcn_fdot2(wpk[j + 4],  __builtin_bit_cast(half2v, hp[j + 4]),  a1, false);
                a2 = __builtin_amdgcn_fdot2(wpk[j + 8],  __builtin_bit_cast(half2v, hp[j + 8]),  a2, false);
                a3 = __builtin_amdgcn_fdot2(wpk[j + 12], __builtin_bit_cast(half2v, hp[j + 12]), a3, false);
            }
            float gs = (a0 + a1) + (a2 + a3);       // = cs * (gi + whh@h)

            float e = __builtin_amdgcn_exp2f(gs);
            float r = __builtin_amdgcn_rcpf(1.0f + e);
            float v = fmaf(cm, r, ca);              // z (lanes<32) or n (lanes>=32)

            uint32 zb, nb;
            half_swap(__float_as_uint(v), zb, nb);
            float z_ = __uint_as_float(zb);
            float n_ = __uint_as_float(nb);

            float hnv = fmaf(z_, h_mine - n_, n_);  // (1-z)*n + z*h
            h_mine = hnv;

            int t = rev ? (T_ - 1 - s) : s;
            if (lane < 32)
                out[((size_t)b * T_ + t) * outStride + colbase + lane] = (ushort16)f2bf_bits(hnv);

            // broadcast h for the next step
            uint32 hbv = __float_as_uint(hnv);
            uint32 nbv = (uint32)__builtin_amdgcn_mov_dpp((int)hbv, 0xB1, 0xF, 0xF, true);
            uint32 pk = __builtin_bit_cast(uint32, pkrtz(hnv, __uint_as_float(nbv)));
#pragma unroll
            for (int j = 0; j < 16; j++)
                hp[j] = (uint32)__builtin_amdgcn_readlane(pk, 2 * j);
        }
    }
}

// ---------------------------------------------------------------------------
// Kernel C: dec1-3 + gi2 forward + gi2 reverse (packed-f16 dot2, cs-prescaled)
// ---------------------------------------------------------------------------
__global__ __launch_bounds__(256) void kC(
    const ushort16* __restrict__ ys1,
    const uint32* __restrict__ wp, const float* __restrict__ B32,
    const float* __restrict__ bih2, const float* __restrict__ bhh2,
    const float* __restrict__ bih2r, const float* __restrict__ bhh2r,
    ushort16* __restrict__ gi2f, ushort16* __restrict__ gi2r)
{
    const int row = blockIdx.x * 256 + threadIdx.x;
    float h[C_], hn[C_];
    const uint4* src = (const uint4*)(ys1 + (size_t)row * 32);
#pragma unroll
    for (int k = 0; k < 4; k++) {
        uint4 v = src[k];
        unpack2(v.x, h[8 * k + 0], h[8 * k + 1]);
        unpack2(v.y, h[8 * k + 2], h[8 * k + 3]);
        unpack2(v.z, h[8 * k + 4], h[8 * k + 5]);
        unpack2(v.w, h[8 * k + 6], h[8 * k + 7]);
    }
    uint32 hpk[16];
#pragma unroll 1
    for (int L = 10; L < 13; L++) {
        const uint32* Wp = wp + OFF_W32P + L * 512;
        const float* bb = B32 + L * C_;
#pragma unroll
        for (int k = 0; k < 16; k++) hpk[k] = packpair(h[2*k], h[2*k+1]);
#pragma unroll
        for (int o = 0; o < C_; o++) {
            float a = bb[o];
#pragma unroll
            for (int j = 0; j < 16; j++) a = fd2(Wp[o * 16 + j], hpk[j], a);
            hn[o] = fmaxf(a, 0.0f);
        }
#pragma unroll
        for (int o = 0; o < C_; o++) h[o] = hn[o];
    }
#pragma unroll
    for (int k = 0; k < 16; k++) hpk[k] = packpair(h[2*k], h[2*k+1]);
#pragma unroll 1
    for (int d = 0; d < 2; d++) {
        const uint32* wihp = wp + (d ? OFF_WIH2RP : OFF_WIH2P);
        const float* bi = d ? bih2r : bih2;
        const float* bh = d ? bhh2r : bhh2;
        uint4* dst = (uint4*)((d ? gi2r : gi2f) + (size_t)row * 64);
#pragma unroll
        for (int k = 0; k < 8; k++) {
            uint32 wbuf[4];
#pragma unroll
            for (int p = 0; p < 4; p++) {
                int o0 = k * 8 + p * 2;
                float cs0 = (o0 < 32) ? CSZ : CSN;
                float a0 = bi[32 + o0] + bh[32 + o0];
                float a1 = bi[33 + o0] + bh[33 + o0];
#pragma unroll
                for (int j = 0; j < 16; j++) {
                    a0 = fd2(wihp[o0 * 16 + j],       hpk[j], a0);
                    a1 = fd2(wihp[(o0 + 1) * 16 + j], hpk[j], a1);
                }
                wbuf[p] = f2bf_bits(a0 * cs0) | (f2bf_bits(a1 * cs0) << 16);
            }
            dst[k] = make_uint4(wbuf[0], wbuf[1], wbuf[2], wbuf[3]);
        }
    }
}

// ---------------------------------------------------------------------------
// Kernel E: up1 (64->32) + up2-5 + out head + sigmoid (packed-f16 dot2)
// ---------------------------------------------------------------------------
__global__ __launch_bounds__(256) void kE(
    const ushort16* __restrict__ hcat,
    const uint32* __restrict__ wp, const float* __restrict__ b_up1,
    const float* __restrict__ B32,
    const float* __restrict__ w_out, const float* __restrict__ b_out,
    float* __restrict__ outp)
{
    const int row = blockIdx.x * 256 + threadIdx.x;
    float h64[64];
    const uint4* src = (const uint4*)(hcat + (size_t)row * 64);
#pragma unroll
    for (int k = 0; k < 8; k++) {
        uint4 v = src[k];
        unpack2(v.x, h64[8 * k + 0], h64[8 * k + 1]);
        unpack2(v.y, h64[8 * k + 2], h64[8 * k + 3]);
        unpack2(v.z, h64[8 * k + 4], h64[8 * k + 5]);
        unpack2(v.w, h64[8 * k + 6], h64[8 * k + 7]);
    }
    uint32 h64pk[32];
#pragma unroll
    for (int k = 0; k < 32; k++) h64pk[k] = packpair(h64[2*k], h64[2*k+1]);

    float h[C_], hn[C_];
    const uint32* wup = wp + OFF_WUP1P;
#pragma unroll
    for (int o = 0; o < C_; o++) {
        float a = b_up1[o];
#pragma unroll
        for (int j = 0; j < 32; j++) a = fd2(wup[o * 32 + j], h64pk[j], a);
        h[o] = fmaxf(a, 0.0f);
    }
    uint32 hpk[16];
#pragma unroll 1
    for (int L = 13; L < 17; L++) {
        const uint32* Wp = wp + OFF_W32P + L * 512;
        const float* bb = B32 + L * C_;
#pragma unroll
        for (int k = 0; k < 16; k++) hpk[k] = packpair(h[2*k], h[2*k+1]);
#pragma unroll
        for (int o = 0; o < C_; o++) {
            float a = bb[o];
#pragma unroll
            for (int j = 0; j < 16; j++) a = fd2(Wp[o * 16 + j], hpk[j], a);
            hn[o] = fmaxf(a, 0.0f);
        }
#pragma unroll
        for (int o = 0; o < C_; o++) h[o] = hn[o];
    }
    float r0 = b_out[0], r1 = b_out[1];
#pragma unroll
    for (int j = 0; j < C_; j++) {
        r0 = fmaf(h[j], w_out[j], r0);
        r1 = fmaf(h[j], w_out[32 + j], r1);
    }
    float2 res = make_float2(fast_sigmoid(r0), fast_sigmoid(r1));
    ((float2*)outp)[row] = res;
}

// ---------------------------------------------------------------------------
extern "C" void kernel_launch(void* const* d_in, const int* in_sizes, int n_in,
                              void* d_out, int out_size, void* d_ws, size_t ws_size,
                              hipStream_t stream) {
    const float* x     = (const float*)d_in[0];
    const float* w_in  = (const float*)d_in[1];
    const float* b_in  = (const float*)d_in[2];
    const float* W32   = (const float*)d_in[3];
    const float* B32   = (const float*)d_in[4];
    const float* w_up1 = (const float*)d_in[5];
    const float* b_up1 = (const float*)d_in[6];
    const float* w_out = (const float*)d_in[7];
    const float* b_out = (const float*)d_in[8];
    const float* wih1  = (const float*)d_in[9];
    const float* whh1  = (const float*)d_in[10];
    const float* bih1  = (const float*)d_in[11];
    const float* bhh1  = (const float*)d_in[12];
    const float* wih2  = (const float*)d_in[13];
    const float* whh2  = (const float*)d_in[14];
    const float* bih2  = (const float*)d_in[15];
    const float* bhh2  = (const float*)d_in[16];
    const float* wih2r = (const float*)d_in[17];
    const float* whh2r = (const float*)d_in[18];
    const float* bih2r = (const float*)d_in[19];
    const float* bhh2r = (const float*)d_in[20];

    const size_t NB = (size_t)B_ * T_;  // 262144 rows
    // Workspace layout (112 MB + 52 KB): gi2f aliases gi1 (dead after gru1).
    ushort16* gi1  = (ushort16*)d_ws;        // [NB][64] bf16 : 32 MB
    ushort16* gi2f = gi1;                    // aliases gi1
    ushort16* gi2r = gi1  + NB * 64;         // 32 MB
    ushort16* ys1  = gi2r + NB * 64;         // [NB][32] bf16 : 16 MB
    ushort16* hcat = ys1  + NB * 32;         // [NB][64] bf16 : 32 MB
    uint32*   wpak = (uint32*)(hcat + NB * 64);  // packed f16 weights : 52 KB

    const int rowBlocks = (int)(NB / 256);   // 1024

    kPack<<<1, 256, 0, stream>>>(w_in, W32, w_up1, wih1, wih2, wih2r, wpak);
    kA<<<rowBlocks, 256, 0, stream>>>(x, b_in, wpak, B32, bih1, bhh1, gi1);
    kGru<<<64, 64, 0, stream>>>(gi1, gi1, whh1, whh1, ys1, 32, 0, 0);
    kC<<<rowBlocks, 256, 0, stream>>>(ys1, wpak, B32, bih2, bhh2, bih2r, bhh2r,
                                      gi2f, gi2r);
    kGru<<<128, 64, 0, stream>>>(gi2f, gi2r, whh2, whh2r, hcat, 64, 0, 32);
    kE<<<rowBlocks, 256, 0, stream>>>(hcat, wpak, b_up1, B32, w_out, b_out,
                                      (float*)d_out);
}